// Round 1
// baseline (298.995 us; speedup 1.0000x reference)
//
#include <hip/hip_runtime.h>

typedef unsigned short u16;
typedef unsigned int   u32;
typedef short bf16x8 __attribute__((ext_vector_type(8)));
typedef float f32x4  __attribute__((ext_vector_type(4)));

#define MFMA(a,b,c) __builtin_amdgcn_mfma_f32_16x16x32_bf16((a),(b),(c),0,0,0)
#define MB (1u<<20)

__device__ __forceinline__ u16 f2bf(float x) {
  u32 u = __builtin_bit_cast(u32, x);
  u32 r = (u + 0x7FFFu + ((u >> 16) & 1u)) >> 16;   // RNE
  return (u16)r;
}
__device__ __forceinline__ float bf2f(u16 b) {
  u32 u = ((u32)b) << 16;
  return __builtin_bit_cast(float, u);
}
__device__ __forceinline__ void async16(void* lds, const void* g) {
  __builtin_amdgcn_global_load_lds(
      (const __attribute__((address_space(1))) u32*)g,
      (__attribute__((address_space(3))) u32*)lds, 16, 0, 0);
}

// ---------------------------------------------------------------------------
// ws layout (bytes):
//  0MB Xq_hi | 4 Xq_lo | 8 Xk_hi | 12 Xk_lo | 16 Xv_hi | 20 Xv_lo
// 24 Wq_hi | 26 Wq_lo | 28 Wk_hi | 30 Wk_lo | 32 Wv_hi | 34 Wv_lo | 36 Wo_hi | 38 Wo_lo
// 40 Qp_hi | 44 Qp_lo | 48 Kp_hi | 52 Kp_lo | 56 Vp_hi | 60 Vp_lo
// reuse after projections:  0 Vt_hi | 4 Vt_lo | 8 At_hi | 12 At_lo
// ---------------------------------------------------------------------------

// ---------------- presplit: f32 -> (hi,lo) bf16 ----------------------------
__global__ __launch_bounds__(256) void presplit_kernel(
    const float* q, const float* k, const float* v,
    const float* wq, const float* wk, const float* wv, const float* wo,
    char* ws)
{
  int y = blockIdx.y;
  const float* srcs[7] = {q, k, v, wq, wk, wv, wo};
  size_t hoffv = (y < 3) ? (size_t)y * (8*MB) : (size_t)(24*MB) + (size_t)(y-3) * (4*MB);
  size_t loffv = hoffv + ((y < 3) ? (size_t)(4*MB) : (size_t)(2*MB));
  int n = (y < 3) ? (2*1024*1024) : (1024*1024);
  int idx = (blockIdx.x * 256 + threadIdx.x) * 4;
  if (idx >= n) return;
  float4 x = *(const float4*)(srcs[y] + idx);
  u16 h0 = f2bf(x.x), h1 = f2bf(x.y), h2 = f2bf(x.z), h3 = f2bf(x.w);
  u16 l0 = f2bf(x.x - bf2f(h0)), l1 = f2bf(x.y - bf2f(h1));
  u16 l2 = f2bf(x.z - bf2f(h2)), l3 = f2bf(x.w - bf2f(h3));
  ushort4 hv; hv.x = h0; hv.y = h1; hv.z = h2; hv.w = h3;
  ushort4 lv; lv.x = l0; lv.y = l1; lv.z = l2; lv.w = l3;
  *(ushort4*)(ws + hoffv + (size_t)idx * 2) = hv;
  *(ushort4*)(ws + loffv + (size_t)idx * 2) = lv;
}

// ---------------- split-precision GEMM  C = A @ B^T ------------------------
// M=2048 N=1024 K=1024, tile 128x64, BK=64, 4 waves (2x2), 64x32 per wave.
#define A_H 0
#define A_L 16384
#define B_H 32768
#define B_L 40960
#define GEMM_LDS 49152

__device__ __forceinline__ void gemm_core(char* smem,
    const u16* __restrict__ Ah, const u16* __restrict__ Al,
    const u16* __restrict__ Bh, const u16* __restrict__ Bl,
    const float* __restrict__ bias, float scale,
    u16* __restrict__ Oh, u16* __restrict__ Ol, float* __restrict__ Of, int mode)
{
  const int t = threadIdx.x, w = t >> 6, lane = t & 63;
  const int l15 = lane & 15, l4 = lane >> 4;
  const int bx = blockIdx.x;
  const int m0 = (bx >> 4) * 128;
  const int n0 = (bx & 15) * 64;
  const int mw = (w >> 1) * 64, nw = (w & 1) * 32;

  f32x4 acc[4][2];
  const f32x4 z4 = {0.f, 0.f, 0.f, 0.f};
  #pragma unroll
  for (int i = 0; i < 4; ++i)
    #pragma unroll
    for (int j = 0; j < 2; ++j) acc[i][j] = z4;

  for (int kt = 0; kt < 16; ++kt) {
    __syncthreads();
    // stage A hi/lo: 1024 16B-chunks each; XOR-swizzled SOURCE, linear LDS dest
    #pragma unroll
    for (int i = 0; i < 4; ++i) {
      int chunk = w*256 + i*64 + lane;
      int row = chunk >> 3, seg = chunk & 7;
      int ss = seg ^ (row & 7);
      size_t goff = (size_t)(m0 + row) * 1024 + kt*64 + ss*8;
      async16(smem + A_H + chunk*16, Ah + goff);
      async16(smem + A_L + chunk*16, Al + goff);
    }
    #pragma unroll
    for (int i = 0; i < 2; ++i) {
      int chunk = w*128 + i*64 + lane;
      int row = chunk >> 3, seg = chunk & 7;
      int ss = seg ^ (row & 7);
      size_t goff = (size_t)(n0 + row) * 1024 + kt*64 + ss*8;
      async16(smem + B_H + chunk*16, Bh + goff);
      async16(smem + B_L + chunk*16, Bl + goff);
    }
    __syncthreads();
    #pragma unroll
    for (int kf = 0; kf < 2; ++kf) {
      bf16x8 avh[4], avl[4], bvh[2], bvl[2];
      #pragma unroll
      for (int mf = 0; mf < 4; ++mf) {
        int row = mw + mf*16 + l15;
        int ks = kf*4 + l4;
        int off = row*128 + ((ks ^ (row & 7)) << 4);
        avh[mf] = *(const bf16x8*)(smem + A_H + off);
        avl[mf] = *(const bf16x8*)(smem + A_L + off);
      }
      #pragma unroll
      for (int nf = 0; nf < 2; ++nf) {
        int row = nw + nf*16 + l15;
        int ks = kf*4 + l4;
        int off = row*128 + ((ks ^ (row & 7)) << 4);
        bvh[nf] = *(const bf16x8*)(smem + B_H + off);
        bvl[nf] = *(const bf16x8*)(smem + B_L + off);
      }
      #pragma unroll
      for (int mf = 0; mf < 4; ++mf)
        #pragma unroll
        for (int nf = 0; nf < 2; ++nf) {
          acc[mf][nf] = MFMA(avh[mf], bvh[nf], acc[mf][nf]);
          acc[mf][nf] = MFMA(avh[mf], bvl[nf], acc[mf][nf]);
          acc[mf][nf] = MFMA(avl[mf], bvh[nf], acc[mf][nf]);
        }
    }
  }
  // epilogue
  #pragma unroll
  for (int mf = 0; mf < 4; ++mf)
    #pragma unroll
    for (int nf = 0; nf < 2; ++nf) {
      int colg = n0 + nw + nf*16 + l15;
      float bb = bias[colg];
      #pragma unroll
      for (int r = 0; r < 4; ++r) {
        int rowg = m0 + mw + mf*16 + l4*4 + r;
        float val = (acc[mf][nf][r] + bb) * scale;
        size_t o = (size_t)rowg * 1024 + colg;
        if (mode == 0) {
          u16 hb = f2bf(val);
          Oh[o] = hb;
          Ol[o] = f2bf(val - bf2f(hb));
        } else {
          Of[o] = val;
        }
      }
    }
}

__global__ __launch_bounds__(256, 3) void proj_kernel(char* ws,
    const float* bq, const float* bk, const float* bv)
{
  __shared__ __align__(16) char smem[GEMM_LDS];
  int z = blockIdx.y;
  const u16* Ah = (const u16*)(ws + (size_t)z*(8*MB));
  const u16* Al = (const u16*)(ws + (size_t)z*(8*MB) + 4*MB);
  const u16* Bh = (const u16*)(ws + (size_t)(24*MB) + (size_t)z*(4*MB));
  const u16* Bl = (const u16*)(ws + (size_t)(24*MB) + (size_t)z*(4*MB) + 2*MB);
  u16* Oh = (u16*)(ws + (size_t)(40*MB) + (size_t)z*(8*MB));
  u16* Ol = (u16*)(ws + (size_t)(40*MB) + (size_t)z*(8*MB) + 4*MB);
  const float* bias = (z == 0) ? bq : ((z == 1) ? bk : bv);
  float scale = (z == 0) ? 0.125f : 1.0f;  // fold 1/sqrt(dh) into Q
  gemm_core(smem, Ah, Al, Bh, Bl, bias, scale, Oh, Ol, nullptr, 0);
}

__global__ __launch_bounds__(256, 3) void final_kernel(char* ws, const float* bo, float* out)
{
  __shared__ __align__(16) char smem[GEMM_LDS];
  const u16* Ah = (const u16*)(ws + (size_t)(8*MB));
  const u16* Al = (const u16*)(ws + (size_t)(12*MB));
  const u16* Bh = (const u16*)(ws + (size_t)(36*MB));
  const u16* Bl = (const u16*)(ws + (size_t)(38*MB));
  gemm_core(smem, Ah, Al, Bh, Bl, bo, 1.0f, nullptr, nullptr, out, 1);
}

// ---------------- V transpose: Vp[2048][1024] -> Vt[(b,h,d)][s] ------------
__global__ __launch_bounds__(256) void vtrans_kernel(char* ws)
{
  __shared__ u16 th[64][68];
  __shared__ u16 tl[64][68];
  const u16* Vph = (const u16*)(ws + (size_t)(56*MB));
  const u16* Vpl = (const u16*)(ws + (size_t)(60*MB));
  u16* Vth = (u16*)(ws + 0);
  u16* Vtl = (u16*)(ws + (size_t)(4*MB));
  int id = blockIdx.x;          // 512 = 32 bh * 16 s-chunks
  int bh = id >> 4, sc = id & 15;
  int b = bh >> 4, h = bh & 15;
  int t = threadIdx.x;
  #pragma unroll
  for (int j = 0; j < 16; ++j) {
    int e = t + 256*j;
    int sr = e >> 6, dc = e & 63;
    size_t g = (size_t)(b*1024 + sc*64 + sr) * 1024 + h*64 + dc;
    th[sr][dc] = Vph[g];
    tl[sr][dc] = Vpl[g];
  }
  __syncthreads();
  #pragma unroll
  for (int j = 0; j < 16; ++j) {
    int e = t + 256*j;
    int dr = e >> 6, scl = e & 63;
    size_t g = (size_t)(bh*64 + dr) * 1024 + sc*64 + scl;
    Vth[g] = th[scl][dr];
    Vtl[g] = tl[scl][dr];
  }
}

// ---------------- attention: QK^T -> exact top-170 -> softmax -> PV --------
#define S_STRIDE 4112   // score row stride bytes (1024*4 + 16)
#define P_STRIDE 2064   // P row stride bytes (1024*2 + 16), in-place over scores
#define ATT_LDS (32 * S_STRIDE)
#define KSEL 170

__global__ __launch_bounds__(512, 1) void attn_kernel(char* ws)
{
  __shared__ __align__(16) char smem[ATT_LDS];
  const u16* Qh  = (const u16*)(ws + (size_t)(40*MB));
  const u16* Ql  = (const u16*)(ws + (size_t)(44*MB));
  const u16* Kh  = (const u16*)(ws + (size_t)(48*MB));
  const u16* Kl  = (const u16*)(ws + (size_t)(52*MB));
  const u16* Vth = (const u16*)(ws + 0);
  const u16* Vtl = (const u16*)(ws + (size_t)(4*MB));
  u16* Ath = (u16*)(ws + (size_t)(8*MB));
  u16* Atl = (u16*)(ws + (size_t)(12*MB));

  int t = threadIdx.x, w = t >> 6, lane = t & 63;
  int l15 = lane & 15, l4 = lane >> 4;
  int bid = blockIdx.x;
  int logical = (bid & 7) * 128 + (bid >> 3);   // XCD swizzle: 4 bh per XCD
  int bh = logical >> 5, qt = logical & 31;
  int b = bh >> 4, h = bh & 15;
  int q0 = qt * 32;

  // Q fragments (rows q0..q0+31, scaled Q already in ws)
  bf16x8 qfh[2][2], qfl[2][2];
  #pragma unroll
  for (int mf = 0; mf < 2; ++mf)
    #pragma unroll
    for (int kf = 0; kf < 2; ++kf) {
      size_t o = (size_t)(b*1024 + q0 + mf*16 + l15) * 1024 + h*64 + kf*32 + l4*8;
      qfh[mf][kf] = *(const bf16x8*)(Qh + o);
      qfl[mf][kf] = *(const bf16x8*)(Ql + o);
    }

  // --- QK^T: wave w covers key columns [w*128, w*128+128) ---
  const f32x4 z4 = {0.f, 0.f, 0.f, 0.f};
  #pragma unroll 2
  for (int nf = 0; nf < 8; ++nf) {
    int kpos = w*128 + nf*16 + l15;
    size_t ko = (size_t)(b*1024 + kpos) * 1024 + h*64 + l4*8;
    bf16x8 kh0 = *(const bf16x8*)(Kh + ko);
    bf16x8 kh1 = *(const bf16x8*)(Kh + ko + 32);
    bf16x8 kl0 = *(const bf16x8*)(Kl + ko);
    bf16x8 kl1 = *(const bf16x8*)(Kl + ko + 32);
    #pragma unroll
    for (int mf = 0; mf < 2; ++mf) {
      f32x4 a = z4;
      a = MFMA(qfh[mf][0], kh0, a);
      a = MFMA(qfh[mf][0], kl0, a);
      a = MFMA(qfl[mf][0], kh0, a);
      a = MFMA(qfh[mf][1], kh1, a);
      a = MFMA(qfh[mf][1], kl1, a);
      a = MFMA(qfl[mf][1], kh1, a);
      #pragma unroll
      for (int r = 0; r < 4; ++r) {
        int row = mf*16 + l4*4 + r;
        *(float*)(smem + row*S_STRIDE + (w*128 + nf*16 + l15)*4) = a[r];
      }
    }
  }
  __syncthreads();

  // --- per-row exact top-170 threshold + softmax; P written in-place -------
  // iter j: waves read score rows 8j..8j+7 into regs, barrier, then write P.
  // P row r bytes [2064r, 2064r+2048) only ever overlap score rows already
  // consumed in this or earlier iterations (proven disjoint from later reads).
  for (int j = 0; j < 4; ++j) {
    int r = j*8 + w;
    float v[16];
    #pragma unroll
    for (int i = 0; i < 16; ++i)
      v[i] = *(const float*)(smem + r*S_STRIDE + (lane + 64*i)*4);
    __syncthreads();
    float m = v[0];
    #pragma unroll
    for (int i = 1; i < 16; ++i) m = fmaxf(m, v[i]);
    #pragma unroll
    for (int off = 32; off > 0; off >>= 1) m = fmaxf(m, __shfl_xor(m, off));
    // monotone uint key
    u32 u[16];
    #pragma unroll
    for (int i = 0; i < 16; ++i) {
      u32 x = __builtin_bit_cast(u32, v[i]);
      u[i] = x ^ ((u32)((int)x >> 31) | 0x80000000u);
    }
    // bisection: largest key t with |{u >= t}| >= 170 (exact tie semantics)
    u32 lo = 0u, hi = 0xFFFFFFFFu;
    while (hi - lo > 1u) {
      u32 mid = lo + ((hi - lo) >> 1);
      int c = 0;
      #pragma unroll
      for (int i = 0; i < 16; ++i)
        c += (int)__popcll(__ballot(u[i] >= mid));
      if (c >= KSEL) { lo = mid; if (c == KSEL) break; }
      else hi = mid;
    }
    u32 thr = lo;
    float s = 0.f;
    float p[16];
    #pragma unroll
    for (int i = 0; i < 16; ++i) {
      float e = (u[i] >= thr) ? __expf(v[i] - m) : 0.f;
      p[i] = e; s += e;
    }
    #pragma unroll
    for (int off = 32; off > 0; off >>= 1) s += __shfl_xor(s, off);
    float rinv = 1.f / s;
    #pragma unroll
    for (int i = 0; i < 16; ++i)
      *(u16*)(smem + r*P_STRIDE + (lane + 64*i)*2) = f2bf(p[i] * rinv);
  }
  __syncthreads();

  // --- PV: wave owns output frag (mf = w>>2, nf = w&3); deterministic ------
  int mf = w >> 2, nf = w & 3;
  size_t vo = (size_t)(bh*64 + nf*16 + l15) * 1024 + l4*8;
  f32x4 a = z4;
  #pragma unroll 4
  for (int ks = 0; ks < 32; ++ks) {
    bf16x8 pa = *(const bf16x8*)(smem + (mf*16 + l15)*P_STRIDE + (ks*32 + l4*8)*2);
    bf16x8 vh = *(const bf16x8*)(Vth + vo + ks*32);
    bf16x8 vl = *(const bf16x8*)(Vtl + vo + ks*32);
    a = MFMA(pa, vh, a);
    a = MFMA(pa, vl, a);
  }
  #pragma unroll
  for (int r = 0; r < 4; ++r) {
    float val = a[r];
    u16 hb = f2bf(val);
    size_t o = (size_t)(b*1024 + q0 + mf*16 + l4*4 + r) * 1024 + h*64 + nf*16 + l15;
    Ath[o] = hb;
    Atl[o] = f2bf(val - bf2f(hb));
  }
}

// ---------------------------------------------------------------------------
extern "C" void kernel_launch(void* const* d_in, const int* in_sizes, int n_in,
                              void* d_out, int out_size, void* d_ws, size_t ws_size,
                              hipStream_t stream)
{
  const float* q  = (const float*)d_in[0];
  const float* k  = (const float*)d_in[1];
  const float* v  = (const float*)d_in[2];
  const float* wq = (const float*)d_in[3];
  const float* bq = (const float*)d_in[4];
  const float* wk = (const float*)d_in[5];
  const float* bk = (const float*)d_in[6];
  const float* wv = (const float*)d_in[7];
  const float* bv = (const float*)d_in[8];
  const float* wo = (const float*)d_in[9];
  const float* bo = (const float*)d_in[10];
  float* out = (float*)d_out;
  char* ws = (char*)d_ws;
  if (ws_size < (64ull << 20)) return;  // need 64 MB scratch

  presplit_kernel<<<dim3(2048, 7), 256, 0, stream>>>(q, k, v, wq, wk, wv, wo, ws);
  proj_kernel<<<dim3(256, 3), 256, 0, stream>>>(ws, bq, bk, bv);
  vtrans_kernel<<<512, 256, 0, stream>>>(ws);
  attn_kernel<<<1024, 512, 0, stream>>>(ws);
  final_kernel<<<256, 256, 0, stream>>>(ws, bo, out);
}

// Round 2
// 262.439 us; speedup vs baseline: 1.1393x; 1.1393x over previous
//
#include <hip/hip_runtime.h>

typedef unsigned short u16;
typedef unsigned int   u32;
typedef short bf16x8 __attribute__((ext_vector_type(8)));
typedef float f32x4  __attribute__((ext_vector_type(4)));

#define MFMA(a,b,c) __builtin_amdgcn_mfma_f32_16x16x32_bf16((a),(b),(c),0,0,0)
#define MB (1u<<20)

__device__ __forceinline__ u16 f2bf(float x) {
  u32 u = __builtin_bit_cast(u32, x);
  u32 r = (u + 0x7FFFu + ((u >> 16) & 1u)) >> 16;   // RNE
  return (u16)r;
}
__device__ __forceinline__ float bf2f(u16 b) {
  u32 u = ((u32)b) << 16;
  return __builtin_bit_cast(float, u);
}
__device__ __forceinline__ void async16(void* lds, const void* g) {
  __builtin_amdgcn_global_load_lds(
      (const __attribute__((address_space(1))) u32*)g,
      (__attribute__((address_space(3))) u32*)lds, 16, 0, 0);
}

// ---------------------------------------------------------------------------
// ws layout (bytes):
//  0MB Xq_hi | 4 Xq_lo | 8 Xk_hi | 12 Xk_lo | 16 Xv_hi | 20 Xv_lo
// 24 Wq_hi | 26 Wq_lo | 28 Wk_hi | 30 Wk_lo | 32 Wv_hi | 34 Wv_lo | 36 Wo_hi | 38 Wo_lo
// 40 Qp_hi | 44 Qp_lo | 48 Kp_hi | 52 Kp_lo | 56 Vp_hi | 60 Vp_lo
// reuse after projections:  0 Vt_hi | 4 Vt_lo | 8 At_hi | 12 At_lo
// ---------------------------------------------------------------------------

// ---------------- presplit: f32 -> (hi,lo) bf16 ----------------------------
__global__ __launch_bounds__(256) void presplit_kernel(
    const float* q, const float* k, const float* v,
    const float* wq, const float* wk, const float* wv, const float* wo,
    char* ws)
{
  int y = blockIdx.y;
  const float* srcs[7] = {q, k, v, wq, wk, wv, wo};
  size_t hoffv = (y < 3) ? (size_t)y * (8*MB) : (size_t)(24*MB) + (size_t)(y-3) * (4*MB);
  size_t loffv = hoffv + ((y < 3) ? (size_t)(4*MB) : (size_t)(2*MB));
  int n = (y < 3) ? (2*1024*1024) : (1024*1024);
  int idx = (blockIdx.x * 256 + threadIdx.x) * 4;
  if (idx >= n) return;
  float4 x = *(const float4*)(srcs[y] + idx);
  u16 h0 = f2bf(x.x), h1 = f2bf(x.y), h2 = f2bf(x.z), h3 = f2bf(x.w);
  u16 l0 = f2bf(x.x - bf2f(h0)), l1 = f2bf(x.y - bf2f(h1));
  u16 l2 = f2bf(x.z - bf2f(h2)), l3 = f2bf(x.w - bf2f(h3));
  ushort4 hv; hv.x = h0; hv.y = h1; hv.z = h2; hv.w = h3;
  ushort4 lv; lv.x = l0; lv.y = l1; lv.z = l2; lv.w = l3;
  *(ushort4*)(ws + hoffv + (size_t)idx * 2) = hv;
  *(ushort4*)(ws + loffv + (size_t)idx * 2) = lv;
}

// ---------------- split-precision GEMM  C = A @ B^T ------------------------
// M=2048 N=1024 K=1024, tile 128x64, BK=64, 4 waves (2x2), 64x32 per wave.
#define A_H 0
#define A_L 16384
#define B_H 32768
#define B_L 40960
#define GEMM_LDS 49152

__device__ __forceinline__ void gemm_core(char* smem,
    const u16* __restrict__ Ah, const u16* __restrict__ Al,
    const u16* __restrict__ Bh, const u16* __restrict__ Bl,
    const float* __restrict__ bias, float scale,
    u16* __restrict__ Oh, u16* __restrict__ Ol, float* __restrict__ Of, int mode)
{
  const int t = threadIdx.x, w = t >> 6, lane = t & 63;
  const int l15 = lane & 15, l4 = lane >> 4;
  const int bx = blockIdx.x;
  const int m0 = (bx >> 4) * 128;
  const int n0 = (bx & 15) * 64;
  const int mw = (w >> 1) * 64, nw = (w & 1) * 32;

  f32x4 acc[4][2];
  const f32x4 z4 = {0.f, 0.f, 0.f, 0.f};
  #pragma unroll
  for (int i = 0; i < 4; ++i)
    #pragma unroll
    for (int j = 0; j < 2; ++j) acc[i][j] = z4;

  for (int kt = 0; kt < 16; ++kt) {
    __syncthreads();
    // stage A hi/lo: 1024 16B-chunks each; XOR-swizzled SOURCE, linear LDS dest
    #pragma unroll
    for (int i = 0; i < 4; ++i) {
      int chunk = w*256 + i*64 + lane;
      int row = chunk >> 3, seg = chunk & 7;
      int ss = seg ^ (row & 7);
      size_t goff = (size_t)(m0 + row) * 1024 + kt*64 + ss*8;
      async16(smem + A_H + chunk*16, Ah + goff);
      async16(smem + A_L + chunk*16, Al + goff);
    }
    #pragma unroll
    for (int i = 0; i < 2; ++i) {
      int chunk = w*128 + i*64 + lane;
      int row = chunk >> 3, seg = chunk & 7;
      int ss = seg ^ (row & 7);
      size_t goff = (size_t)(n0 + row) * 1024 + kt*64 + ss*8;
      async16(smem + B_H + chunk*16, Bh + goff);
      async16(smem + B_L + chunk*16, Bl + goff);
    }
    __syncthreads();
    #pragma unroll
    for (int kf = 0; kf < 2; ++kf) {
      bf16x8 avh[4], avl[4], bvh[2], bvl[2];
      #pragma unroll
      for (int mf = 0; mf < 4; ++mf) {
        int row = mw + mf*16 + l15;
        int ks = kf*4 + l4;
        int off = row*128 + ((ks ^ (row & 7)) << 4);
        avh[mf] = *(const bf16x8*)(smem + A_H + off);
        avl[mf] = *(const bf16x8*)(smem + A_L + off);
      }
      #pragma unroll
      for (int nf = 0; nf < 2; ++nf) {
        int row = nw + nf*16 + l15;
        int ks = kf*4 + l4;
        int off = row*128 + ((ks ^ (row & 7)) << 4);
        bvh[nf] = *(const bf16x8*)(smem + B_H + off);
        bvl[nf] = *(const bf16x8*)(smem + B_L + off);
      }
      #pragma unroll
      for (int mf = 0; mf < 4; ++mf)
        #pragma unroll
        for (int nf = 0; nf < 2; ++nf) {
          acc[mf][nf] = MFMA(avh[mf], bvh[nf], acc[mf][nf]);
          acc[mf][nf] = MFMA(avh[mf], bvl[nf], acc[mf][nf]);
          acc[mf][nf] = MFMA(avl[mf], bvh[nf], acc[mf][nf]);
        }
    }
  }
  // epilogue
  #pragma unroll
  for (int mf = 0; mf < 4; ++mf)
    #pragma unroll
    for (int nf = 0; nf < 2; ++nf) {
      int colg = n0 + nw + nf*16 + l15;
      float bb = bias[colg];
      #pragma unroll
      for (int r = 0; r < 4; ++r) {
        int rowg = m0 + mw + mf*16 + l4*4 + r;
        float val = (acc[mf][nf][r] + bb) * scale;
        size_t o = (size_t)rowg * 1024 + colg;
        if (mode == 0) {
          u16 hb = f2bf(val);
          Oh[o] = hb;
          Ol[o] = f2bf(val - bf2f(hb));
        } else {
          Of[o] = val;
        }
      }
    }
}

__global__ __launch_bounds__(256, 3) void proj_kernel(char* ws,
    const float* bq, const float* bk, const float* bv)
{
  __shared__ __align__(16) char smem[GEMM_LDS];
  int z = blockIdx.y;
  const u16* Ah = (const u16*)(ws + (size_t)z*(8*MB));
  const u16* Al = (const u16*)(ws + (size_t)z*(8*MB) + 4*MB);
  const u16* Bh = (const u16*)(ws + (size_t)(24*MB) + (size_t)z*(4*MB));
  const u16* Bl = (const u16*)(ws + (size_t)(24*MB) + (size_t)z*(4*MB) + 2*MB);
  u16* Oh = (u16*)(ws + (size_t)(40*MB) + (size_t)z*(8*MB));
  u16* Ol = (u16*)(ws + (size_t)(40*MB) + (size_t)z*(8*MB) + 4*MB);
  const float* bias = (z == 0) ? bq : ((z == 1) ? bk : bv);
  float scale = (z == 0) ? 0.125f : 1.0f;  // fold 1/sqrt(dh) into Q
  gemm_core(smem, Ah, Al, Bh, Bl, bias, scale, Oh, Ol, nullptr, 0);
}

__global__ __launch_bounds__(256, 3) void final_kernel(char* ws, const float* bo, float* out)
{
  __shared__ __align__(16) char smem[GEMM_LDS];
  const u16* Ah = (const u16*)(ws + (size_t)(8*MB));
  const u16* Al = (const u16*)(ws + (size_t)(12*MB));
  const u16* Bh = (const u16*)(ws + (size_t)(36*MB));
  const u16* Bl = (const u16*)(ws + (size_t)(38*MB));
  gemm_core(smem, Ah, Al, Bh, Bl, bo, 1.0f, nullptr, nullptr, out, 1);
}

// ---------------- V transpose: Vp[2048][1024] -> Vt[(b,h,d)][s] ------------
__global__ __launch_bounds__(256) void vtrans_kernel(char* ws)
{
  __shared__ u16 th[64][68];
  __shared__ u16 tl[64][68];
  const u16* Vph = (const u16*)(ws + (size_t)(56*MB));
  const u16* Vpl = (const u16*)(ws + (size_t)(60*MB));
  u16* Vth = (u16*)(ws + 0);
  u16* Vtl = (u16*)(ws + (size_t)(4*MB));
  int id = blockIdx.x;          // 512 = 32 bh * 16 s-chunks
  int bh = id >> 4, sc = id & 15;
  int b = bh >> 4, h = bh & 15;
  int t = threadIdx.x;
  #pragma unroll
  for (int j = 0; j < 16; ++j) {
    int e = t + 256*j;
    int sr = e >> 6, dc = e & 63;
    size_t g = (size_t)(b*1024 + sc*64 + sr) * 1024 + h*64 + dc;
    th[sr][dc] = Vph[g];
    tl[sr][dc] = Vpl[g];
  }
  __syncthreads();
  #pragma unroll
  for (int j = 0; j < 16; ++j) {
    int e = t + 256*j;
    int dr = e >> 6, scl = e & 63;
    size_t g = (size_t)(bh*64 + dr) * 1024 + sc*64 + scl;
    Vth[g] = th[scl][dr];
    Vtl[g] = tl[scl][dr];
  }
}

// ---------------- attention: QK^T -> exact top-170 -> softmax -> PV --------
// 16 q-rows per block, 512 threads (8 waves), 2048 blocks, 2 blocks/CU.
#define S_STRIDE 4112   // score row stride bytes (1024*4 + 16)
#define P_STRIDE 2064   // P row stride bytes (1024*2 + 16), in-place over scores
#define PART_OFF 65792  // 16*4112, PV partial buffer (4 KB)
#define ATT_LDS (PART_OFF + 4096)
#define KSEL 170

__global__ __launch_bounds__(512, 4) void attn_kernel(char* ws)
{
  __shared__ __align__(16) char smem[ATT_LDS];
  const u16* Qh  = (const u16*)(ws + (size_t)(40*MB));
  const u16* Ql  = (const u16*)(ws + (size_t)(44*MB));
  const u16* Kh  = (const u16*)(ws + (size_t)(48*MB));
  const u16* Kl  = (const u16*)(ws + (size_t)(52*MB));
  const u16* Vth = (const u16*)(ws + 0);
  const u16* Vtl = (const u16*)(ws + (size_t)(4*MB));
  u16* Ath = (u16*)(ws + (size_t)(8*MB));
  u16* Atl = (u16*)(ws + (size_t)(12*MB));

  int t = threadIdx.x, w = t >> 6, lane = t & 63;
  int l15 = lane & 15, l4 = lane >> 4;
  int bid = blockIdx.x;
  int logical = (bid & 7) * 256 + (bid >> 3);   // XCD swizzle: 4 bh per XCD
  int bh = logical >> 6, qt = logical & 63;
  int b = bh >> 4, h = bh & 15;
  int q0 = qt * 16;

  // Q fragments (rows q0..q0+15, scaled Q already in ws)
  bf16x8 qfh[2], qfl[2];
  #pragma unroll
  for (int kf = 0; kf < 2; ++kf) {
    size_t o = (size_t)(b*1024 + q0 + l15) * 1024 + h*64 + kf*32 + l4*8;
    qfh[kf] = *(const bf16x8*)(Qh + o);
    qfl[kf] = *(const bf16x8*)(Ql + o);
  }

  // --- QK^T: wave w covers key columns [w*128, w*128+128) ---
  const f32x4 z4 = {0.f, 0.f, 0.f, 0.f};
  #pragma unroll 2
  for (int nf = 0; nf < 8; ++nf) {
    int kpos = w*128 + nf*16 + l15;
    size_t ko = (size_t)(b*1024 + kpos) * 1024 + h*64 + l4*8;
    bf16x8 kh0 = *(const bf16x8*)(Kh + ko);
    bf16x8 kh1 = *(const bf16x8*)(Kh + ko + 32);
    bf16x8 kl0 = *(const bf16x8*)(Kl + ko);
    bf16x8 kl1 = *(const bf16x8*)(Kl + ko + 32);
    f32x4 a = z4;
    a = MFMA(qfh[0], kh0, a);
    a = MFMA(qfh[0], kl0, a);
    a = MFMA(qfl[0], kh0, a);
    a = MFMA(qfh[1], kh1, a);
    a = MFMA(qfh[1], kl1, a);
    a = MFMA(qfl[1], kh1, a);
    #pragma unroll
    for (int r = 0; r < 4; ++r) {
      int row = l4*4 + r;
      *(float*)(smem + row*S_STRIDE + (w*128 + nf*16 + l15)*4) = a[r];
    }
  }
  __syncthreads();

  // --- per-row exact top-170 threshold + softmax; P written in-place -------
  // j=0: rows 0..7 read; barrier; P rows 0..7 written (bytes < 16496, below
  // score row 4..; all of rows 0..7 already consumed). j=1: rows 8..15
  // (bytes >= 32896) disjoint from P rows 0..7; same read/barrier/write.
  for (int j = 0; j < 2; ++j) {
    int r = j*8 + w;
    f32x4 v4[4];
    #pragma unroll
    for (int i = 0; i < 4; ++i)
      v4[i] = *(const f32x4*)(smem + r*S_STRIDE + lane*16 + i*1024);
    __syncthreads();
    // row max
    float m = v4[0][0];
    #pragma unroll
    for (int i = 0; i < 4; ++i)
      #pragma unroll
      for (int e = 0; e < 4; ++e) m = fmaxf(m, v4[i][e]);
    #pragma unroll
    for (int off = 32; off > 0; off >>= 1) m = fmaxf(m, __shfl_xor(m, off));
    // float-space bisection for the 170th largest value.
    // invariant: count(>=lo) >= 170 (or lo = m-16 clamp; dropped keys have
    // weight < e^-16), count(>=hi) < 170.  break when count(mid)==170 (exact
    // top-170 set) or lo,hi adjacent (lo == 170th value; ties kept like ref).
    float lo = m - 16.f, hi = m;
    float thr;
    int iter = 0;
    while (true) {
      float mid = 0.5f * (lo + hi);
      if (!(mid > lo) || !(mid < hi) || iter++ > 60) { thr = lo; break; }
      int c = 0;
      #pragma unroll
      for (int i = 0; i < 4; ++i)
        #pragma unroll
        for (int e = 0; e < 4; ++e)
          c += (int)__popcll(__ballot(v4[i][e] >= mid));
      if (c >= KSEL) { lo = mid; if (c == KSEL) { thr = mid; break; } }
      else hi = mid;
    }
    // softmax over selected
    float s = 0.f;
    float p[16];
    #pragma unroll
    for (int i = 0; i < 4; ++i)
      #pragma unroll
      for (int e = 0; e < 4; ++e) {
        float val = v4[i][e];
        float ex = (val >= thr) ? __expf(val - m) : 0.f;
        p[i*4+e] = ex; s += ex;
      }
    #pragma unroll
    for (int off = 32; off > 0; off >>= 1) s += __shfl_xor(s, off);
    float rinv = 1.f / s;
    #pragma unroll
    for (int i = 0; i < 4; ++i) {
      ushort4 pw;
      pw.x = f2bf(p[i*4+0] * rinv);
      pw.y = f2bf(p[i*4+1] * rinv);
      pw.z = f2bf(p[i*4+2] * rinv);
      pw.w = f2bf(p[i*4+3] * rinv);
      *(ushort4*)(smem + r*P_STRIDE + lane*8 + i*512) = pw;
    }
  }
  __syncthreads();

  // --- PV: frag f = w&3 (cols f*16..), half = w>>2 splits ks range ---------
  int f = w & 3, half = w >> 2;
  size_t vo = (size_t)(bh*64 + f*16 + l15) * 1024 + half*512 + l4*8;
  f32x4 a = z4;
  #pragma unroll 4
  for (int ks = 0; ks < 16; ++ks) {
    bf16x8 pa = *(const bf16x8*)(smem + l15*P_STRIDE + ((half*16 + ks)*32 + l4*8)*2);
    bf16x8 vh = *(const bf16x8*)(Vth + vo + ks*32);
    bf16x8 vl = *(const bf16x8*)(Vtl + vo + ks*32);
    a = MFMA(pa, vh, a);
    a = MFMA(pa, vl, a);
  }
  if (half == 1)
    *(f32x4*)(smem + PART_OFF + (f*64 + lane)*16) = a;
  __syncthreads();
  if (half == 0) {
    f32x4 o4 = *(const f32x4*)(smem + PART_OFF + (f*64 + lane)*16);
    #pragma unroll
    for (int r = 0; r < 4; ++r) {
      float val = a[r] + o4[r];
      u16 hb = f2bf(val);
      size_t o = (size_t)(b*1024 + q0 + l4*4 + r) * 1024 + h*64 + f*16 + l15;
      Ath[o] = hb;
      Atl[o] = f2bf(val - bf2f(hb));
    }
  }
}

// ---------------------------------------------------------------------------
extern "C" void kernel_launch(void* const* d_in, const int* in_sizes, int n_in,
                              void* d_out, int out_size, void* d_ws, size_t ws_size,
                              hipStream_t stream)
{
  const float* q  = (const float*)d_in[0];
  const float* k  = (const float*)d_in[1];
  const float* v  = (const float*)d_in[2];
  const float* wq = (const float*)d_in[3];
  const float* bq = (const float*)d_in[4];
  const float* wk = (const float*)d_in[5];
  const float* bk = (const float*)d_in[6];
  const float* wv = (const float*)d_in[7];
  const float* bv = (const float*)d_in[8];
  const float* wo = (const float*)d_in[9];
  const float* bo = (const float*)d_in[10];
  float* out = (float*)d_out;
  char* ws = (char*)d_ws;
  if (ws_size < (64ull << 20)) return;  // need 64 MB scratch

  presplit_kernel<<<dim3(2048, 7), 256, 0, stream>>>(q, k, v, wq, wk, wv, wo, ws);
  proj_kernel<<<dim3(256, 3), 256, 0, stream>>>(ws, bq, bk, bv);
  vtrans_kernel<<<512, 256, 0, stream>>>(ws);
  attn_kernel<<<2048, 512, 0, stream>>>(ws);
  final_kernel<<<256, 256, 0, stream>>>(ws, bo, out);
}

// Round 3
// 186.416 us; speedup vs baseline: 1.6039x; 1.4078x over previous
//
#include <hip/hip_runtime.h>

typedef unsigned short u16;
typedef unsigned int   u32;
typedef short bf16x8 __attribute__((ext_vector_type(8)));
typedef float f32x4  __attribute__((ext_vector_type(4)));

#define MFMA(a,b,c) __builtin_amdgcn_mfma_f32_16x16x32_bf16((a),(b),(c),0,0,0)
#define MB (1u<<20)

__device__ __forceinline__ u16 f2bf(float x) {
  u32 u = __builtin_bit_cast(u32, x);
  u32 r = (u + 0x7FFFu + ((u >> 16) & 1u)) >> 16;   // RNE
  return (u16)r;
}
__device__ __forceinline__ float bf2f(u16 b) {
  u32 u = ((u32)b) << 16;
  return __builtin_bit_cast(float, u);
}
__device__ __forceinline__ void async16(void* lds, const void* g) {
  __builtin_amdgcn_global_load_lds(
      (const __attribute__((address_space(1))) u32*)g,
      (__attribute__((address_space(3))) u32*)lds, 16, 0, 0);
}

// ---------------------------------------------------------------------------
// ws layout (MB):
//  0 Xq_hi | 4 Xq_lo | 8 Xk_hi | 12 Xk_lo | 16 Xv_hi | (20 unused)
// 24 Wq_hi | 26 Wq_lo | 28 Wk_hi | 30 Wk_lo | 32 Wv_hi | 36 Wo_hi
// 40 Qp_hi | 44 Qp_lo | 48 Kp_hi | 52 Kp_lo | 56 Vp_hi
// reuse after proj:  0 Vt_hi | 8 At_hi
// Precision plan: Q,K chains use hi/lo 3-product (score ranking needs ~1e-4);
// V, At, Wo are bf16-hi only (each contributes ~0.001 to output vs 0.0106 thr).
// ---------------------------------------------------------------------------

// ---------------- presplit: f32 -> (hi[,lo]) bf16 --------------------------
__global__ __launch_bounds__(256) void presplit_kernel(
    const float* q, const float* k, const float* v,
    const float* wq, const float* wk, const float* wv, const float* wo,
    char* ws)
{
  int y = blockIdx.y;
  const float* srcs[7] = {q, k, v, wq, wk, wv, wo};
  size_t hoffv = (y < 3) ? (size_t)y * (8*MB) : (size_t)(24*MB) + (size_t)(y-3) * (4*MB);
  size_t loffv = hoffv + ((y < 3) ? (size_t)(4*MB) : (size_t)(2*MB));
  bool wlo = (y == 0) || (y == 1) || (y == 3) || (y == 4);
  int n = (y < 3) ? (2*1024*1024) : (1024*1024);
  int idx = (blockIdx.x * 256 + threadIdx.x) * 4;
  if (idx >= n) return;
  float4 x = *(const float4*)(srcs[y] + idx);
  ushort4 hv; hv.x = f2bf(x.x); hv.y = f2bf(x.y); hv.z = f2bf(x.z); hv.w = f2bf(x.w);
  *(ushort4*)(ws + hoffv + (size_t)idx * 2) = hv;
  if (wlo) {
    ushort4 lv;
    lv.x = f2bf(x.x - bf2f(hv.x)); lv.y = f2bf(x.y - bf2f(hv.y));
    lv.z = f2bf(x.z - bf2f(hv.z)); lv.w = f2bf(x.w - bf2f(hv.w));
    *(ushort4*)(ws + loffv + (size_t)idx * 2) = lv;
  }
}

// ---------------- proj GEMM  C = A @ B^T  (128x128 tile, 8 waves) ----------
// M=2048 N=1024 K=1024.  z=0 (Q) and z=1 (K): 3-product split; z=2 (V): hi only.
#define PA_H 0
#define PA_L 16384
#define PB_H 32768
#define PB_L 49152
#define PROJ_LDS 65536

__global__ __launch_bounds__(512, 4) void proj_kernel(char* ws,
    const float* bq, const float* bk, const float* bv)
{
  __shared__ __align__(16) char smem[PROJ_LDS];
  const int z = blockIdx.y;
  const bool split = (z < 2);
  const u16* Ah = (const u16*)(ws + (size_t)z*(8*MB));
  const u16* Al = (const u16*)(ws + (size_t)z*(8*MB) + 4*MB);
  const u16* Bh = (const u16*)(ws + (size_t)(24*MB) + (size_t)z*(4*MB));
  const u16* Bl = (const u16*)(ws + (size_t)(24*MB) + (size_t)z*(4*MB) + 2*MB);
  u16* Oh = (u16*)(ws + (size_t)(40*MB) + (size_t)z*(8*MB));
  u16* Ol = (u16*)(ws + (size_t)(40*MB) + (size_t)z*(8*MB) + 4*MB);
  const float* bias = (z == 0) ? bq : ((z == 1) ? bk : bv);
  const float scale = (z == 0) ? 0.125f : 1.0f;   // fold 1/sqrt(dh) into Q

  const int t = threadIdx.x, w = t >> 6, lane = t & 63;
  const int l15 = lane & 15, l4 = lane >> 4;
  const int m0 = (blockIdx.x >> 3) * 128;
  const int n0 = (blockIdx.x & 7) * 128;
  const int mw = (w >> 2) * 64, nw = (w & 3) * 32;

  f32x4 acc[4][2];
  const f32x4 z4 = {0.f, 0.f, 0.f, 0.f};
  #pragma unroll
  for (int i = 0; i < 4; ++i)
    #pragma unroll
    for (int j = 0; j < 2; ++j) acc[i][j] = z4;

  for (int kt = 0; kt < 16; ++kt) {
    __syncthreads();
    #pragma unroll
    for (int i = 0; i < 2; ++i) {
      int chunk = w*128 + i*64 + lane;          // 1024 chunks of 16B per tile
      int row = chunk >> 3, seg = chunk & 7;
      int ss = seg ^ (row & 7);
      size_t ga = (size_t)(m0 + row) * 1024 + kt*64 + ss*8;
      size_t gb = (size_t)(n0 + row) * 1024 + kt*64 + ss*8;
      async16(smem + PA_H + chunk*16, Ah + ga);
      async16(smem + PB_H + chunk*16, Bh + gb);
      if (split) {
        async16(smem + PA_L + chunk*16, Al + ga);
        async16(smem + PB_L + chunk*16, Bl + gb);
      }
    }
    __syncthreads();
    #pragma unroll
    for (int kf = 0; kf < 2; ++kf) {
      bf16x8 avh[4], avl[4], bvh[2], bvl[2];
      #pragma unroll
      for (int mf = 0; mf < 4; ++mf) {
        int row = mw + mf*16 + l15;
        int ks = kf*4 + l4;
        int off = row*128 + ((ks ^ (row & 7)) << 4);
        avh[mf] = *(const bf16x8*)(smem + PA_H + off);
        if (split) avl[mf] = *(const bf16x8*)(smem + PA_L + off);
      }
      #pragma unroll
      for (int nf = 0; nf < 2; ++nf) {
        int row = nw + nf*16 + l15;
        int ks = kf*4 + l4;
        int off = row*128 + ((ks ^ (row & 7)) << 4);
        bvh[nf] = *(const bf16x8*)(smem + PB_H + off);
        if (split) bvl[nf] = *(const bf16x8*)(smem + PB_L + off);
      }
      #pragma unroll
      for (int mf = 0; mf < 4; ++mf)
        #pragma unroll
        for (int nf = 0; nf < 2; ++nf) {
          acc[mf][nf] = MFMA(avh[mf], bvh[nf], acc[mf][nf]);
          if (split) {
            acc[mf][nf] = MFMA(avh[mf], bvl[nf], acc[mf][nf]);
            acc[mf][nf] = MFMA(avl[mf], bvh[nf], acc[mf][nf]);
          }
        }
    }
  }
  #pragma unroll
  for (int mf = 0; mf < 4; ++mf)
    #pragma unroll
    for (int nf = 0; nf < 2; ++nf) {
      int colg = n0 + nw + nf*16 + l15;
      float bb = bias[colg];
      #pragma unroll
      for (int r = 0; r < 4; ++r) {
        int rowg = m0 + mw + mf*16 + l4*4 + r;
        float val = (acc[mf][nf][r] + bb) * scale;
        size_t o = (size_t)rowg * 1024 + colg;
        u16 hb = f2bf(val);
        Oh[o] = hb;
        if (split) Ol[o] = f2bf(val - bf2f(hb));
      }
    }
}

// ---------------- final GEMM  out = At @ Wo^T + bo  (hi-only, f32 out) -----
#define FA_H 0
#define FB_H 16384
#define FIN_LDS 24576

__global__ __launch_bounds__(256, 3) void final_kernel(char* ws, const float* bo, float* out)
{
  __shared__ __align__(16) char smem[FIN_LDS];
  const u16* Ah = (const u16*)(ws + (size_t)(8*MB));
  const u16* Bh = (const u16*)(ws + (size_t)(36*MB));
  const int t = threadIdx.x, w = t >> 6, lane = t & 63;
  const int l15 = lane & 15, l4 = lane >> 4;
  const int m0 = (blockIdx.x >> 4) * 128;
  const int n0 = (blockIdx.x & 15) * 64;
  const int mw = (w >> 1) * 64, nw = (w & 1) * 32;

  f32x4 acc[4][2];
  const f32x4 z4 = {0.f, 0.f, 0.f, 0.f};
  #pragma unroll
  for (int i = 0; i < 4; ++i)
    #pragma unroll
    for (int j = 0; j < 2; ++j) acc[i][j] = z4;

  for (int kt = 0; kt < 16; ++kt) {
    __syncthreads();
    #pragma unroll
    for (int i = 0; i < 4; ++i) {             // A: 1024 chunks
      int chunk = w*256 + i*64 + lane;
      int row = chunk >> 3, seg = chunk & 7;
      int ss = seg ^ (row & 7);
      async16(smem + FA_H + chunk*16, Ah + (size_t)(m0 + row) * 1024 + kt*64 + ss*8);
    }
    #pragma unroll
    for (int i = 0; i < 2; ++i) {             // B: 512 chunks
      int chunk = w*128 + i*64 + lane;
      if (chunk < 512) {
        int row = chunk >> 3, seg = chunk & 7;
        int ss = seg ^ (row & 7);
        async16(smem + FB_H + chunk*16, Bh + (size_t)(n0 + row) * 1024 + kt*64 + ss*8);
      }
    }
    __syncthreads();
    #pragma unroll
    for (int kf = 0; kf < 2; ++kf) {
      bf16x8 avh[4], bvh[2];
      #pragma unroll
      for (int mf = 0; mf < 4; ++mf) {
        int row = mw + mf*16 + l15;
        int ks = kf*4 + l4;
        avh[mf] = *(const bf16x8*)(smem + FA_H + row*128 + ((ks ^ (row & 7)) << 4));
      }
      #pragma unroll
      for (int nf = 0; nf < 2; ++nf) {
        int row = nw + nf*16 + l15;
        int ks = kf*4 + l4;
        bvh[nf] = *(const bf16x8*)(smem + FB_H + row*128 + ((ks ^ (row & 7)) << 4));
      }
      #pragma unroll
      for (int mf = 0; mf < 4; ++mf)
        #pragma unroll
        for (int nf = 0; nf < 2; ++nf)
          acc[mf][nf] = MFMA(avh[mf], bvh[nf], acc[mf][nf]);
    }
  }
  #pragma unroll
  for (int mf = 0; mf < 4; ++mf)
    #pragma unroll
    for (int nf = 0; nf < 2; ++nf) {
      int colg = n0 + nw + nf*16 + l15;
      float bb = bo[colg];
      #pragma unroll
      for (int r = 0; r < 4; ++r) {
        int rowg = m0 + mw + mf*16 + l4*4 + r;
        out[(size_t)rowg * 1024 + colg] = acc[mf][nf][r] + bb;
      }
    }
}

// ---------------- V transpose: Vp_hi[2048][1024] -> Vt[(b,h,d)][s] ---------
__global__ __launch_bounds__(256) void vtrans_kernel(char* ws)
{
  __shared__ u16 th[64][68];
  const u16* Vph = (const u16*)(ws + (size_t)(56*MB));
  u16* Vth = (u16*)(ws + 0);
  int id = blockIdx.x;          // 512 = 32 bh * 16 s-chunks
  int bh = id >> 4, sc = id & 15;
  int b = bh >> 4, h = bh & 15;
  int t = threadIdx.x;
  #pragma unroll
  for (int j = 0; j < 16; ++j) {
    int e = t + 256*j;
    int sr = e >> 6, dc = e & 63;
    th[sr][dc] = Vph[(size_t)(b*1024 + sc*64 + sr) * 1024 + h*64 + dc];
  }
  __syncthreads();
  #pragma unroll
  for (int j = 0; j < 16; ++j) {
    int e = t + 256*j;
    int dr = e >> 6, scl = e & 63;
    Vth[(size_t)(bh*64 + dr) * 1024 + sc*64 + scl] = th[scl][dr];
  }
}

// ---------------- attention: QK^T -> exact top-170 -> softmax -> PV --------
// 16 q-rows per block, 512 threads (8 waves), 2048 blocks, 2 blocks/CU.
#define S_STRIDE 4112   // score row stride bytes (1024*4 + 16)
#define P_STRIDE 2064   // P row stride bytes, in-place over scores
#define PART_OFF 65792  // 16*4112, PV partial buffer (4 KB)
#define ATT_LDS (PART_OFF + 4096)
#define KSEL 170

__global__ __launch_bounds__(512, 4) void attn_kernel(char* ws)
{
  __shared__ __align__(16) char smem[ATT_LDS];
  const u16* Qh  = (const u16*)(ws + (size_t)(40*MB));
  const u16* Ql  = (const u16*)(ws + (size_t)(44*MB));
  const u16* Kh  = (const u16*)(ws + (size_t)(48*MB));
  const u16* Kl  = (const u16*)(ws + (size_t)(52*MB));
  const u16* Vth = (const u16*)(ws + 0);
  u16* Ath = (u16*)(ws + (size_t)(8*MB));

  int t = threadIdx.x, w = t >> 6, lane = t & 63;
  int l15 = lane & 15, l4 = lane >> 4;
  int bid = blockIdx.x;
  int logical = (bid & 7) * 256 + (bid >> 3);   // XCD swizzle: 4 bh per XCD
  int bh = logical >> 6, qt = logical & 63;
  int b = bh >> 4, h = bh & 15;
  int q0 = qt * 16;

  const f32x4 z4 = {0.f, 0.f, 0.f, 0.f};

  // ---- QK^T with 2-batch-deep K prefetch (8 loads per batch) --------------
  bf16x8 kb[2][2][4];           // [buf][nf-in-pair][kh0,kh1,kl0,kl1]
  size_t kbase = (size_t)(b*1024 + w*128 + l15) * 1024 + h*64 + l4*8;
#define LOADK(BUF, PAIR) do { \
    _Pragma("unroll") \
    for (int j_ = 0; j_ < 2; ++j_) { \
      size_t ko_ = kbase + (size_t)(((PAIR)*2 + j_) * 16) * 1024; \
      kb[BUF][j_][0] = *(const bf16x8*)(Kh + ko_); \
      kb[BUF][j_][1] = *(const bf16x8*)(Kh + ko_ + 32); \
      kb[BUF][j_][2] = *(const bf16x8*)(Kl + ko_); \
      kb[BUF][j_][3] = *(const bf16x8*)(Kl + ko_ + 32); \
    } } while (0)

  LOADK(0, 0);
  LOADK(1, 1);

  bf16x8 qfh[2], qfl[2];
  #pragma unroll
  for (int kf = 0; kf < 2; ++kf) {
    size_t o = (size_t)(b*1024 + q0 + l15) * 1024 + h*64 + kf*32 + l4*8;
    qfh[kf] = *(const bf16x8*)(Qh + o);
    qfl[kf] = *(const bf16x8*)(Ql + o);
  }

  #pragma unroll
  for (int pr = 0; pr < 4; ++pr) {
    #pragma unroll
    for (int j = 0; j < 2; ++j) {
      int nf = pr*2 + j;
      f32x4 a0 = z4, a1 = z4;              // split chains (kf=0 / kf=1)
      a0 = MFMA(qfh[0], kb[pr & 1][j][0], a0);
      a1 = MFMA(qfh[1], kb[pr & 1][j][1], a1);
      a0 = MFMA(qfl[0], kb[pr & 1][j][0], a0);
      a1 = MFMA(qfl[1], kb[pr & 1][j][1], a1);
      a0 = MFMA(qfh[0], kb[pr & 1][j][2], a0);
      a1 = MFMA(qfh[1], kb[pr & 1][j][3], a1);
      #pragma unroll
      for (int r = 0; r < 4; ++r)
        *(float*)(smem + (l4*4 + r)*S_STRIDE + (w*128 + nf*16 + l15)*4) = a0[r] + a1[r];
    }
    if (pr == 0) LOADK(0, 2);
    if (pr == 1) LOADK(1, 3);
  }
  __syncthreads();

  // ---- dual-row exact top-170 + softmax; single aliasing barrier ----------
  {
    int rA = w, rB = w + 8;
    f32x4 va[4], vb4[4];
    #pragma unroll
    for (int i = 0; i < 4; ++i) {
      va[i]  = *(const f32x4*)(smem + rA*S_STRIDE + lane*16 + i*1024);
      vb4[i] = *(const f32x4*)(smem + rB*S_STRIDE + lane*16 + i*1024);
    }
    __syncthreads();   // all 16 score rows consumed; P writes now safe

    float mA = va[0][0], mB = vb4[0][0];
    #pragma unroll
    for (int i = 0; i < 4; ++i)
      #pragma unroll
      for (int e = 0; e < 4; ++e) {
        mA = fmaxf(mA, va[i][e]);
        mB = fmaxf(mB, vb4[i][e]);
      }
    #pragma unroll
    for (int off = 32; off > 0; off >>= 1) {
      mA = fmaxf(mA, __shfl_xor(mA, off));
      mB = fmaxf(mB, __shfl_xor(mB, off));
    }

    // interleaved float-space bisection; exact tie semantics (see r2 proof)
    float loA = mA - 16.f, hiA = mA, thrA = 0.f;
    float loB = mB - 16.f, hiB = mB, thrB = 0.f;
    bool fA = false, fB = false;
    for (int it = 0; it < 26; ++it) {
      if (fA && fB) break;
      float midA = 0.5f * (loA + hiA);
      float midB = 0.5f * (loB + hiB);
      int cA = 0, cB = 0;
      #pragma unroll
      for (int i = 0; i < 4; ++i)
        #pragma unroll
        for (int e = 0; e < 4; ++e) {
          cA += (int)__popcll(__ballot(va[i][e]  >= midA));
          cB += (int)__popcll(__ballot(vb4[i][e] >= midB));
        }
      if (cA >= KSEL) loA = midA; else hiA = midA;
      if (cA == KSEL && !fA) { thrA = midA; fA = true; }
      if (cB >= KSEL) loB = midB; else hiB = midB;
      if (cB == KSEL && !fB) { thrB = midB; fB = true; }
    }
    if (!fA) thrA = loA;
    if (!fB) thrB = loB;

    float sA = 0.f, sB = 0.f;
    #pragma unroll
    for (int i = 0; i < 4; ++i)
      #pragma unroll
      for (int e = 0; e < 4; ++e) {
        float xa = va[i][e], xb = vb4[i][e];
        float ea = (xa >= thrA) ? __expf(xa - mA) : 0.f;
        float eb = (xb >= thrB) ? __expf(xb - mB) : 0.f;
        va[i][e] = ea; vb4[i][e] = eb;
        sA += ea; sB += eb;
      }
    #pragma unroll
    for (int off = 32; off > 0; off >>= 1) {
      sA += __shfl_xor(sA, off);
      sB += __shfl_xor(sB, off);
    }
    float rA_ = 1.f / sA, rB_ = 1.f / sB;
    #pragma unroll
    for (int i = 0; i < 4; ++i) {
      ushort4 pa, pb;
      pa.x = f2bf(va[i][0] * rA_);  pa.y = f2bf(va[i][1] * rA_);
      pa.z = f2bf(va[i][2] * rA_);  pa.w = f2bf(va[i][3] * rA_);
      pb.x = f2bf(vb4[i][0] * rB_); pb.y = f2bf(vb4[i][1] * rB_);
      pb.z = f2bf(vb4[i][2] * rB_); pb.w = f2bf(vb4[i][3] * rB_);
      *(ushort4*)(smem + rA*P_STRIDE + lane*8 + i*512) = pa;
      *(ushort4*)(smem + rB*P_STRIDE + lane*8 + i*512) = pb;
    }
  }
  __syncthreads();

  // ---- PV (V-hi only) with 2-batch-deep V prefetch ------------------------
  int f = w & 3, half = w >> 2;
  size_t vo = (size_t)(bh*64 + f*16 + l15) * 1024 + half*512 + l4*8;
  bf16x8 vb[2][4];
#define LOADV(BUF, G) do { \
    _Pragma("unroll") \
    for (int j_ = 0; j_ < 4; ++j_) \
      vb[BUF][j_] = *(const bf16x8*)(Vth + vo + (size_t)(((G)*4 + j_) * 32)); \
    } while (0)

  LOADV(0, 0);
  LOADV(1, 1);
  f32x4 ac0 = z4, ac1 = z4;
  #pragma unroll
  for (int g = 0; g < 4; ++g) {
    #pragma unroll
    for (int j = 0; j < 4; ++j) {
      int ksl = g*4 + j;
      bf16x8 pa = *(const bf16x8*)(smem + l15*P_STRIDE + (half*16 + ksl)*64 + l4*16);
      if (j & 1) ac1 = MFMA(pa, vb[g & 1][j], ac1);
      else       ac0 = MFMA(pa, vb[g & 1][j], ac0);
    }
    if (g == 0) LOADV(0, 2);
    if (g == 1) LOADV(1, 3);
  }
  f32x4 a = ac0 + ac1;

  if (half == 1)
    *(f32x4*)(smem + PART_OFF + (f*64 + lane)*16) = a;
  __syncthreads();
  if (half == 0) {
    f32x4 o4 = *(const f32x4*)(smem + PART_OFF + (f*64 + lane)*16);
    #pragma unroll
    for (int r = 0; r < 4; ++r) {
      float val = a[r] + o4[r];
      size_t o = (size_t)(b*1024 + q0 + l4*4 + r) * 1024 + h*64 + f*16 + l15;
      Ath[o] = f2bf(val);
    }
  }
}

// ---------------------------------------------------------------------------
extern "C" void kernel_launch(void* const* d_in, const int* in_sizes, int n_in,
                              void* d_out, int out_size, void* d_ws, size_t ws_size,
                              hipStream_t stream)
{
  const float* q  = (const float*)d_in[0];
  const float* k  = (const float*)d_in[1];
  const float* v  = (const float*)d_in[2];
  const float* wq = (const float*)d_in[3];
  const float* bq = (const float*)d_in[4];
  const float* wk = (const float*)d_in[5];
  const float* bk = (const float*)d_in[6];
  const float* wv = (const float*)d_in[7];
  const float* bv = (const float*)d_in[8];
  const float* wo = (const float*)d_in[9];
  const float* bo = (const float*)d_in[10];
  float* out = (float*)d_out;
  char* ws = (char*)d_ws;
  if (ws_size < (64ull << 20)) return;  // need 64 MB scratch

  presplit_kernel<<<dim3(2048, 7), 256, 0, stream>>>(q, k, v, wq, wk, wv, wo, ws);
  proj_kernel<<<dim3(128, 3), 512, 0, stream>>>(ws, bq, bk, bv);
  vtrans_kernel<<<512, 256, 0, stream>>>(ws);
  attn_kernel<<<2048, 512, 0, stream>>>(ws);
  final_kernel<<<256, 256, 0, stream>>>(ws, bo, out);
}

// Round 4
// 182.452 us; speedup vs baseline: 1.6388x; 1.0217x over previous
//
#include <hip/hip_runtime.h>

typedef unsigned short u16;
typedef unsigned int   u32;
typedef short bf16x8 __attribute__((ext_vector_type(8)));
typedef float f32x4  __attribute__((ext_vector_type(4)));

#define MFMA(a,b,c) __builtin_amdgcn_mfma_f32_16x16x32_bf16((a),(b),(c),0,0,0)
#define MB (1u<<20)

__device__ __forceinline__ u16 f2bf(float x) {
  u32 u = __builtin_bit_cast(u32, x);
  u32 r = (u + 0x7FFFu + ((u >> 16) & 1u)) >> 16;   // RNE
  return (u16)r;
}
__device__ __forceinline__ float bf2f(u16 b) {
  u32 u = ((u32)b) << 16;
  return __builtin_bit_cast(float, u);
}
__device__ __forceinline__ void async16(void* lds, const void* g) {
  __builtin_amdgcn_global_load_lds(
      (const __attribute__((address_space(1))) u32*)g,
      (__attribute__((address_space(3))) u32*)lds, 16, 0, 0);
}

// ---------------------------------------------------------------------------
// ws layout (MB):
//  0 Xq_hi | 4 Xq_lo | 8 Xk_hi | 12 Xk_lo | 16 Xv_hi | (20 unused)
// 24 Wq_hi | 26 Wq_lo | 28 Wk_hi | 30 Wk_lo | 32 Wv_hi | 36 Wo_hi
// 40 Qp_hi | 44 Qp_lo | 48 Kp_hi | 52 Kp_lo | 56 Vp_hi
// reuse after proj:  0 Vt_hi | 8 At_hi
// Precision plan: Q,K chains use hi/lo 3-product (score ranking needs ~1e-4);
// V, At, Wo are bf16-hi only (each contributes ~0.001 to output vs 0.0106 thr).
// ---------------------------------------------------------------------------

// ---------------- presplit: f32 -> (hi[,lo]) bf16 --------------------------
__global__ __launch_bounds__(256) void presplit_kernel(
    const float* q, const float* k, const float* v,
    const float* wq, const float* wk, const float* wv, const float* wo,
    char* ws)
{
  int y = blockIdx.y;
  const float* srcs[7] = {q, k, v, wq, wk, wv, wo};
  size_t hoffv = (y < 3) ? (size_t)y * (8*MB) : (size_t)(24*MB) + (size_t)(y-3) * (4*MB);
  size_t loffv = hoffv + ((y < 3) ? (size_t)(4*MB) : (size_t)(2*MB));
  bool wlo = (y == 0) || (y == 1) || (y == 3) || (y == 4);
  int n = (y < 3) ? (2*1024*1024) : (1024*1024);
  int idx = (blockIdx.x * 256 + threadIdx.x) * 4;
  if (idx >= n) return;
  float4 x = *(const float4*)(srcs[y] + idx);
  ushort4 hv; hv.x = f2bf(x.x); hv.y = f2bf(x.y); hv.z = f2bf(x.z); hv.w = f2bf(x.w);
  *(ushort4*)(ws + hoffv + (size_t)idx * 2) = hv;
  if (wlo) {
    ushort4 lv;
    lv.x = f2bf(x.x - bf2f(hv.x)); lv.y = f2bf(x.y - bf2f(hv.y));
    lv.z = f2bf(x.z - bf2f(hv.z)); lv.w = f2bf(x.w - bf2f(hv.w));
    *(ushort4*)(ws + loffv + (size_t)idx * 2) = lv;
  }
}

// ---------------- proj GEMM  C = A @ B^T  (128x128 tile, 8 waves) ----------
// M=2048 N=1024 K=1024.  z=0 (Q) and z=1 (K): 3-product split; z=2 (V): hi only.
#define PA_H 0
#define PA_L 16384
#define PB_H 32768
#define PB_L 49152
#define PROJ_LDS 65536

__global__ __launch_bounds__(512, 4) void proj_kernel(char* ws,
    const float* bq, const float* bk, const float* bv)
{
  __shared__ __align__(16) char smem[PROJ_LDS];
  const int z = blockIdx.y;
  const bool split = (z < 2);
  const u16* Ah = (const u16*)(ws + (size_t)z*(8*MB));
  const u16* Al = (const u16*)(ws + (size_t)z*(8*MB) + 4*MB);
  const u16* Bh = (const u16*)(ws + (size_t)(24*MB) + (size_t)z*(4*MB));
  const u16* Bl = (const u16*)(ws + (size_t)(24*MB) + (size_t)z*(4*MB) + 2*MB);
  u16* Oh = (u16*)(ws + (size_t)(40*MB) + (size_t)z*(8*MB));
  u16* Ol = (u16*)(ws + (size_t)(40*MB) + (size_t)z*(8*MB) + 4*MB);
  const float* bias = (z == 0) ? bq : ((z == 1) ? bk : bv);
  const float scale = (z == 0) ? 0.125f : 1.0f;   // fold 1/sqrt(dh) into Q

  const int t = threadIdx.x, w = t >> 6, lane = t & 63;
  const int l15 = lane & 15, l4 = lane >> 4;
  const int m0 = (blockIdx.x >> 3) * 128;
  const int n0 = (blockIdx.x & 7) * 128;
  const int mw = (w >> 2) * 64, nw = (w & 3) * 32;

  f32x4 acc[4][2];
  const f32x4 z4 = {0.f, 0.f, 0.f, 0.f};
  #pragma unroll
  for (int i = 0; i < 4; ++i)
    #pragma unroll
    for (int j = 0; j < 2; ++j) acc[i][j] = z4;

  for (int kt = 0; kt < 16; ++kt) {
    __syncthreads();
    #pragma unroll
    for (int i = 0; i < 2; ++i) {
      int chunk = w*128 + i*64 + lane;          // 1024 chunks of 16B per tile
      int row = chunk >> 3, seg = chunk & 7;
      int ss = seg ^ (row & 7);
      size_t ga = (size_t)(m0 + row) * 1024 + kt*64 + ss*8;
      size_t gb = (size_t)(n0 + row) * 1024 + kt*64 + ss*8;
      async16(smem + PA_H + chunk*16, Ah + ga);
      async16(smem + PB_H + chunk*16, Bh + gb);
      if (split) {
        async16(smem + PA_L + chunk*16, Al + ga);
        async16(smem + PB_L + chunk*16, Bl + gb);
      }
    }
    __syncthreads();
    #pragma unroll
    for (int kf = 0; kf < 2; ++kf) {
      bf16x8 avh[4], avl[4], bvh[2], bvl[2];
      #pragma unroll
      for (int mf = 0; mf < 4; ++mf) {
        int row = mw + mf*16 + l15;
        int ks = kf*4 + l4;
        int off = row*128 + ((ks ^ (row & 7)) << 4);
        avh[mf] = *(const bf16x8*)(smem + PA_H + off);
        if (split) avl[mf] = *(const bf16x8*)(smem + PA_L + off);
      }
      #pragma unroll
      for (int nf = 0; nf < 2; ++nf) {
        int row = nw + nf*16 + l15;
        int ks = kf*4 + l4;
        int off = row*128 + ((ks ^ (row & 7)) << 4);
        bvh[nf] = *(const bf16x8*)(smem + PB_H + off);
        if (split) bvl[nf] = *(const bf16x8*)(smem + PB_L + off);
      }
      #pragma unroll
      for (int mf = 0; mf < 4; ++mf)
        #pragma unroll
        for (int nf = 0; nf < 2; ++nf) {
          acc[mf][nf] = MFMA(avh[mf], bvh[nf], acc[mf][nf]);
          if (split) {
            acc[mf][nf] = MFMA(avh[mf], bvl[nf], acc[mf][nf]);
            acc[mf][nf] = MFMA(avl[mf], bvh[nf], acc[mf][nf]);
          }
        }
    }
  }
  #pragma unroll
  for (int mf = 0; mf < 4; ++mf)
    #pragma unroll
    for (int nf = 0; nf < 2; ++nf) {
      int colg = n0 + nw + nf*16 + l15;
      float bb = bias[colg];
      #pragma unroll
      for (int r = 0; r < 4; ++r) {
        int rowg = m0 + mw + mf*16 + l4*4 + r;
        float val = (acc[mf][nf][r] + bb) * scale;
        size_t o = (size_t)rowg * 1024 + colg;
        u16 hb = f2bf(val);
        Oh[o] = hb;
        if (split) Ol[o] = f2bf(val - bf2f(hb));
      }
    }
}

// ---------------- final GEMM  out = At @ Wo^T + bo  (hi-only, f32 out) -----
#define FA_H 0
#define FB_H 16384
#define FIN_LDS 24576

__global__ __launch_bounds__(256, 3) void final_kernel(char* ws, const float* bo, float* out)
{
  __shared__ __align__(16) char smem[FIN_LDS];
  const u16* Ah = (const u16*)(ws + (size_t)(8*MB));
  const u16* Bh = (const u16*)(ws + (size_t)(36*MB));
  const int t = threadIdx.x, w = t >> 6, lane = t & 63;
  const int l15 = lane & 15, l4 = lane >> 4;
  const int m0 = (blockIdx.x >> 4) * 128;
  const int n0 = (blockIdx.x & 15) * 64;
  const int mw = (w >> 1) * 64, nw = (w & 1) * 32;

  f32x4 acc[4][2];
  const f32x4 z4 = {0.f, 0.f, 0.f, 0.f};
  #pragma unroll
  for (int i = 0; i < 4; ++i)
    #pragma unroll
    for (int j = 0; j < 2; ++j) acc[i][j] = z4;

  for (int kt = 0; kt < 16; ++kt) {
    __syncthreads();
    #pragma unroll
    for (int i = 0; i < 4; ++i) {             // A: 1024 chunks
      int chunk = w*256 + i*64 + lane;
      int row = chunk >> 3, seg = chunk & 7;
      int ss = seg ^ (row & 7);
      async16(smem + FA_H + chunk*16, Ah + (size_t)(m0 + row) * 1024 + kt*64 + ss*8);
    }
    #pragma unroll
    for (int i = 0; i < 2; ++i) {             // B: 512 chunks
      int chunk = w*128 + i*64 + lane;
      if (chunk < 512) {
        int row = chunk >> 3, seg = chunk & 7;
        int ss = seg ^ (row & 7);
        async16(smem + FB_H + chunk*16, Bh + (size_t)(n0 + row) * 1024 + kt*64 + ss*8);
      }
    }
    __syncthreads();
    #pragma unroll
    for (int kf = 0; kf < 2; ++kf) {
      bf16x8 avh[4], bvh[2];
      #pragma unroll
      for (int mf = 0; mf < 4; ++mf) {
        int row = mw + mf*16 + l15;
        int ks = kf*4 + l4;
        avh[mf] = *(const bf16x8*)(smem + FA_H + row*128 + ((ks ^ (row & 7)) << 4));
      }
      #pragma unroll
      for (int nf = 0; nf < 2; ++nf) {
        int row = nw + nf*16 + l15;
        int ks = kf*4 + l4;
        bvh[nf] = *(const bf16x8*)(smem + FB_H + row*128 + ((ks ^ (row & 7)) << 4));
      }
      #pragma unroll
      for (int mf = 0; mf < 4; ++mf)
        #pragma unroll
        for (int nf = 0; nf < 2; ++nf)
          acc[mf][nf] = MFMA(avh[mf], bvh[nf], acc[mf][nf]);
    }
  }
  #pragma unroll
  for (int mf = 0; mf < 4; ++mf)
    #pragma unroll
    for (int nf = 0; nf < 2; ++nf) {
      int colg = n0 + nw + nf*16 + l15;
      float bb = bo[colg];
      #pragma unroll
      for (int r = 0; r < 4; ++r) {
        int rowg = m0 + mw + mf*16 + l4*4 + r;
        out[(size_t)rowg * 1024 + colg] = acc[mf][nf][r] + bb;
      }
    }
}

// ---------------- V transpose: Vp_hi[2048][1024] -> Vt[(b,h,d)][s] ---------
__global__ __launch_bounds__(256) void vtrans_kernel(char* ws)
{
  __shared__ u16 th[64][68];
  const u16* Vph = (const u16*)(ws + (size_t)(56*MB));
  u16* Vth = (u16*)(ws + 0);
  int id = blockIdx.x;          // 512 = 32 bh * 16 s-chunks
  int bh = id >> 4, sc = id & 15;
  int b = bh >> 4, h = bh & 15;
  int t = threadIdx.x;
  #pragma unroll
  for (int j = 0; j < 16; ++j) {
    int e = t + 256*j;
    int sr = e >> 6, dc = e & 63;
    th[sr][dc] = Vph[(size_t)(b*1024 + sc*64 + sr) * 1024 + h*64 + dc];
  }
  __syncthreads();
  #pragma unroll
  for (int j = 0; j < 16; ++j) {
    int e = t + 256*j;
    int dr = e >> 6, scl = e & 63;
    Vth[(size_t)(bh*64 + dr) * 1024 + sc*64 + scl] = th[scl][dr];
  }
}

// ---------------- attention: QK^T -> exact top-170 -> softmax -> PV --------
// 16 q-rows per block, 512 threads (8 waves), 2048 blocks, 2 blocks/CU.
#define S_STRIDE 4112   // score row stride bytes (1024*4 + 16)
#define P_STRIDE 2064   // P row stride bytes, in-place over scores
#define PART_OFF 65792  // 16*4112, PV partial buffer (4 KB)
#define ATT_LDS (PART_OFF + 4096)
#define KSEL 170

__global__ __launch_bounds__(512, 4) void attn_kernel(char* ws)
{
  __shared__ __align__(16) char smem[ATT_LDS];
  const u16* Qh  = (const u16*)(ws + (size_t)(40*MB));
  const u16* Ql  = (const u16*)(ws + (size_t)(44*MB));
  const u16* Kh  = (const u16*)(ws + (size_t)(48*MB));
  const u16* Kl  = (const u16*)(ws + (size_t)(52*MB));
  const u16* Vth = (const u16*)(ws + 0);
  u16* Ath = (u16*)(ws + (size_t)(8*MB));

  int t = threadIdx.x, w = t >> 6, lane = t & 63;
  int l15 = lane & 15, l4 = lane >> 4;
  int bid = blockIdx.x;
  int logical = (bid & 7) * 256 + (bid >> 3);   // XCD swizzle: 4 bh per XCD
  int bh = logical >> 6, qt = logical & 63;
  int b = bh >> 4, h = bh & 15;
  int q0 = qt * 16;

  const f32x4 z4 = {0.f, 0.f, 0.f, 0.f};

  // ---- Q fragments FIRST (so MFMA's qf wait doesn't drain the K pipe) -----
  bf16x8 qfh[2], qfl[2];
  #pragma unroll
  for (int kf = 0; kf < 2; ++kf) {
    size_t o = (size_t)(b*1024 + q0 + l15) * 1024 + h*64 + kf*32 + l4*8;
    qfh[kf] = *(const bf16x8*)(Qh + o);
    qfl[kf] = *(const bf16x8*)(Ql + o);
  }

  // ---- QK^T with 2-batch-deep K prefetch (8 loads per batch) --------------
  bf16x8 kb[2][2][4];           // [buf][nf-in-pair][kh0,kh1,kl0,kl1]
  size_t kbase = (size_t)(b*1024 + w*128 + l15) * 1024 + h*64 + l4*8;
#define LOADK(BUF, PAIR) do { \
    _Pragma("unroll") \
    for (int j_ = 0; j_ < 2; ++j_) { \
      size_t ko_ = kbase + (size_t)(((PAIR)*2 + j_) * 16) * 1024; \
      kb[BUF][j_][0] = *(const bf16x8*)(Kh + ko_); \
      kb[BUF][j_][1] = *(const bf16x8*)(Kh + ko_ + 32); \
      kb[BUF][j_][2] = *(const bf16x8*)(Kl + ko_); \
      kb[BUF][j_][3] = *(const bf16x8*)(Kl + ko_ + 32); \
    } } while (0)

  LOADK(0, 0);
  LOADK(1, 1);

  #pragma unroll
  for (int pr = 0; pr < 4; ++pr) {
    #pragma unroll
    for (int j = 0; j < 2; ++j) {
      int nf = pr*2 + j;
      f32x4 a0 = z4, a1 = z4;              // split chains (kf=0 / kf=1)
      a0 = MFMA(qfh[0], kb[pr & 1][j][0], a0);
      a1 = MFMA(qfh[1], kb[pr & 1][j][1], a1);
      a0 = MFMA(qfl[0], kb[pr & 1][j][0], a0);
      a1 = MFMA(qfl[1], kb[pr & 1][j][1], a1);
      a0 = MFMA(qfh[0], kb[pr & 1][j][2], a0);
      a1 = MFMA(qfh[1], kb[pr & 1][j][3], a1);
      #pragma unroll
      for (int r = 0; r < 4; ++r)
        *(float*)(smem + (l4*4 + r)*S_STRIDE + (w*128 + nf*16 + l15)*4) = a0[r] + a1[r];
    }
    if (pr == 0) LOADK(0, 2);
    if (pr == 1) LOADK(1, 3);
  }
  __syncthreads();

  // ---- PV geometry + V prefetch buffers (issued early, below) -------------
  int f = w & 3, half = w >> 2;
  size_t vo = (size_t)(bh*64 + f*16 + l15) * 1024 + half*512 + l4*8;
  bf16x8 vb[2][4];
#define LOADV(BUF, G) do { \
    _Pragma("unroll") \
    for (int j_ = 0; j_ < 4; ++j_) \
      vb[BUF][j_] = *(const bf16x8*)(Vth + vo + (size_t)(((G)*4 + j_) * 32)); \
    } while (0)

  // ---- dual-row exact top-170 + softmax; single aliasing barrier ----------
  {
    int rA = w, rB = w + 8;
    f32x4 va[4], vb4[4];
    #pragma unroll
    for (int i = 0; i < 4; ++i) {
      va[i]  = *(const f32x4*)(smem + rA*S_STRIDE + lane*16 + i*1024);
      vb4[i] = *(const f32x4*)(smem + rB*S_STRIDE + lane*16 + i*1024);
    }
    // V prefetch: addresses known; ~3Kcy of selection below hides the latency
    LOADV(0, 0);
    LOADV(1, 1);
    __syncthreads();   // all 16 score rows consumed; P writes now safe

    float mA = va[0][0], mB = vb4[0][0];
    #pragma unroll
    for (int i = 0; i < 4; ++i)
      #pragma unroll
      for (int e = 0; e < 4; ++e) {
        mA = fmaxf(mA, va[i][e]);
        mB = fmaxf(mB, vb4[i][e]);
      }
    #pragma unroll
    for (int off = 32; off > 0; off >>= 1) {
      mA = fmaxf(mA, __shfl_xor(mA, off));
      mB = fmaxf(mB, __shfl_xor(mB, off));
    }

    // Hybrid regula-falsi (iters 0..7) -> pure bisection (8..31).
    // Invariant: count(>=lo) >= 170 > count(>=hi).  Early exit when
    // count(mid)==170 (exact top-170 set).  Terminal fallback thr=lo with
    // float-adjacent bracket == exact 170th value (ties kept like reference).
    float loA = mA - 16.f, hiA = mA, cLoA = 1024.f, cHiA = 1.f;
    float loB = mB - 16.f, hiB = mB, cLoB = 1024.f, cHiB = 1.f;
    float thrA = 0.f, thrB = 0.f;
    bool fA = false, fB = false;
    #pragma unroll 1
    for (int it = 0; it < 32 && !(fA && fB); ++it) {
      float gA, gB;
      if (it < 8) {
        gA = fminf(fmaxf((cLoA - (float)KSEL) / fmaxf(cLoA - cHiA, 1.f), 0.10f), 0.90f);
        gB = fminf(fmaxf((cLoB - (float)KSEL) / fmaxf(cLoB - cHiB, 1.f), 0.10f), 0.90f);
      } else {
        gA = 0.5f; gB = 0.5f;
      }
      float tA = loA + (hiA - loA) * gA;
      float tB = loB + (hiB - loB) * gB;
      if (!(tA > loA && tA < hiA)) { if (!fA) { thrA = loA; fA = true; } tA = loA; }
      if (!(tB > loB && tB < hiB)) { if (!fB) { thrB = loB; fB = true; } tB = loB; }
      int cA = 0, cB = 0;
      #pragma unroll
      for (int i = 0; i < 4; ++i)
        #pragma unroll
        for (int e = 0; e < 4; ++e) {
          cA += (int)__popcll(__ballot(va[i][e]  >= tA));
          cB += (int)__popcll(__ballot(vb4[i][e] >= tB));
        }
      if (!fA) {
        if (cA == KSEL) { thrA = tA; fA = true; }
        else if (cA > KSEL) { loA = tA; cLoA = (float)cA; }
        else { hiA = tA; cHiA = (float)cA; }
      }
      if (!fB) {
        if (cB == KSEL) { thrB = tB; fB = true; }
        else if (cB > KSEL) { loB = tB; cLoB = (float)cB; }
        else { hiB = tB; cHiB = (float)cB; }
      }
    }
    if (!fA) thrA = loA;
    if (!fB) thrB = loB;

    float sA = 0.f, sB = 0.f;
    #pragma unroll
    for (int i = 0; i < 4; ++i)
      #pragma unroll
      for (int e = 0; e < 4; ++e) {
        float xa = va[i][e], xb = vb4[i][e];
        float ea = (xa >= thrA) ? __expf(xa - mA) : 0.f;
        float eb = (xb >= thrB) ? __expf(xb - mB) : 0.f;
        va[i][e] = ea; vb4[i][e] = eb;
        sA += ea; sB += eb;
      }
    #pragma unroll
    for (int off = 32; off > 0; off >>= 1) {
      sA += __shfl_xor(sA, off);
      sB += __shfl_xor(sB, off);
    }
    float rA_ = 1.f / sA, rB_ = 1.f / sB;
    #pragma unroll
    for (int i = 0; i < 4; ++i) {
      ushort4 pa, pb;
      pa.x = f2bf(va[i][0] * rA_);  pa.y = f2bf(va[i][1] * rA_);
      pa.z = f2bf(va[i][2] * rA_);  pa.w = f2bf(va[i][3] * rA_);
      pb.x = f2bf(vb4[i][0] * rB_); pb.y = f2bf(vb4[i][1] * rB_);
      pb.z = f2bf(vb4[i][2] * rB_); pb.w = f2bf(vb4[i][3] * rB_);
      *(ushort4*)(smem + rA*P_STRIDE + lane*8 + i*512) = pa;
      *(ushort4*)(smem + rB*P_STRIDE + lane*8 + i*512) = pb;
    }
  }
  __syncthreads();

  // ---- PV (V-hi only); vb[0],vb[1] already in flight since selection ------
  f32x4 ac0 = z4, ac1 = z4;
  #pragma unroll
  for (int g = 0; g < 4; ++g) {
    #pragma unroll
    for (int j = 0; j < 4; ++j) {
      int ksl = g*4 + j;
      bf16x8 pa = *(const bf16x8*)(smem + l15*P_STRIDE + (half*16 + ksl)*64 + l4*16);
      if (j & 1) ac1 = MFMA(pa, vb[g & 1][j], ac1);
      else       ac0 = MFMA(pa, vb[g & 1][j], ac0);
    }
    if (g == 0) LOADV(0, 2);
    if (g == 1) LOADV(1, 3);
  }
  f32x4 a = ac0 + ac1;

  if (half == 1)
    *(f32x4*)(smem + PART_OFF + (f*64 + lane)*16) = a;
  __syncthreads();
  if (half == 0) {
    f32x4 o4 = *(const f32x4*)(smem + PART_OFF + (f*64 + lane)*16);
    #pragma unroll
    for (int r = 0; r < 4; ++r) {
      float val = a[r] + o4[r];
      size_t o = (size_t)(b*1024 + q0 + l4*4 + r) * 1024 + h*64 + f*16 + l15;
      Ath[o] = f2bf(val);
    }
  }
}

// ---------------------------------------------------------------------------
extern "C" void kernel_launch(void* const* d_in, const int* in_sizes, int n_in,
                              void* d_out, int out_size, void* d_ws, size_t ws_size,
                              hipStream_t stream)
{
  const float* q  = (const float*)d_in[0];
  const float* k  = (const float*)d_in[1];
  const float* v  = (const float*)d_in[2];
  const float* wq = (const float*)d_in[3];
  const float* bq = (const float*)d_in[4];
  const float* wk = (const float*)d_in[5];
  const float* bk = (const float*)d_in[6];
  const float* wv = (const float*)d_in[7];
  const float* bv = (const float*)d_in[8];
  const float* wo = (const float*)d_in[9];
  const float* bo = (const float*)d_in[10];
  float* out = (float*)d_out;
  char* ws = (char*)d_ws;
  if (ws_size < (64ull << 20)) return;  // need 64 MB scratch

  presplit_kernel<<<dim3(2048, 7), 256, 0, stream>>>(q, k, v, wq, wk, wv, wo, ws);
  proj_kernel<<<dim3(128, 3), 512, 0, stream>>>(ws, bq, bk, bv);
  vtrans_kernel<<<512, 256, 0, stream>>>(ws);
  attn_kernel<<<2048, 512, 0, stream>>>(ws);
  final_kernel<<<256, 256, 0, stream>>>(ws, bo, out);
}